// Round 11
// baseline (3249.387 us; speedup 1.0000x reference)
//
#include <hip/hip_runtime.h>

// TimeframeEncoder R11: revert to R8 (known-correct agent-scope rings, 3.15ms)
// and fix its two measured stalls: (1) depth-2 ring lockstep -> DEPTH=4 rings
// (acks lag 3 chunks, jitter absorbed); (2) zero MLP across steps -> B and C
// prefetch step s+1's ring loads (double-buffered regs, fully unrolled loop)
// so the ~900cyc uncached-load latency overlaps step s's MFMAs.
// R9/R10's same-XCD sc0 coherence experiment abandoned (unverifiable; spun).
// 16 groups x 3 blocks (256 thr): A=layer0, B=layer1 h0-GEMM, C=layer1 rec+LN.

#define SEQL 512
#define CH 8
#define NCH 64
#define DEPTH 4

#define RB0  1310720u                   // rings base (weights end 1,277,952)
#define GSTR 1048576u                   // per group: 4x64KB h0 + 4x192KB partials
#define CTRB (RB0 + 16u * GSTR)         // counters: 16 groups x 64 B

typedef __bf16 bf16x8 __attribute__((ext_vector_type(8)));
typedef float f32x4 __attribute__((ext_vector_type(4)));
typedef unsigned long long u64;

__device__ __forceinline__ unsigned short f2bf(float f) {
  unsigned int u = __builtin_bit_cast(unsigned int, f);
  u += 0x7fffu + ((u >> 16) & 1u);
  return (unsigned short)(u >> 16);
}
__device__ __forceinline__ float bf2f(unsigned short u) {
  unsigned int v = ((unsigned int)u) << 16;
  return __builtin_bit_cast(float, v);
}
__device__ __forceinline__ float sigm(float x) { return 1.0f / (1.0f + __expf(-x)); }
__device__ __forceinline__ float tanh_(float x) { return 1.0f - 2.0f / (__expf(2.0f * x) + 1.0f); }
__device__ __forceinline__ float sanit(float v) {
  if (!(v == v)) return 0.f;
  if (isinf(v)) return v > 0.f ? 10.f : -10.f;
  return v;
}

// agent-coherent 8B data access (bypasses stale caches; proven correct in R8)
__device__ __forceinline__ void st8(u64* p, u64 v) {
  __hip_atomic_store(p, v, __ATOMIC_RELAXED, __HIP_MEMORY_SCOPE_AGENT);
}
__device__ __forceinline__ u64 ld8(const u64* p) {
  return __hip_atomic_load(p, __ATOMIC_RELAXED, __HIP_MEMORY_SCOPE_AGENT);
}

// Weight prep (layout verified R1-R8): bf16 B-fragments, tile = 512 ushort,
// lane L holds B[k=(L>>4)*8+j][n=L&15]. Wz0p tiles [0,320) (nt<32,kt<10);
// Wc0p base 320 (nt<16,kt<10); Wz1p base 480 (nt<32,kt<16); Wc1p base 992.
__global__ __launch_bounds__(256) void prep_weights(
    const float* __restrict__ Wz0, const float* __restrict__ Wc0,
    const float* __restrict__ Wz1, const float* __restrict__ Wc1,
    unsigned short* __restrict__ ws) {
  int idx = blockIdx.x * 256 + threadIdx.x;  // 638976 threads
  const float* W;
  int stride, KT, base;
  if (idx < 163840)      { W = Wz0; stride = 768; KT = 10; base = 0; }
  else if (idx < 245760) { W = Wc0; stride = 256; KT = 10; base = 163840; idx -= 163840; }
  else if (idx < 507904) { W = Wz1; stride = 768; KT = 16; base = 245760; idx -= 245760; }
  else                   { W = Wc1; stride = 256; KT = 16; base = 507904; idx -= 507904; }
  int tile = idx >> 9;
  int t = idx & 511;
  int nt = tile / KT;
  int kt = tile - nt * KT;
  int n15 = t & 15;
  int klocal = t >> 4;
  int k = (kt << 5) + klocal;
  int n = (nt << 4) + n15;
  int lane = ((klocal >> 3) << 4) | n15;
  int j = klocal & 7;
  ws[base + (tile << 9) + (lane << 3) + j] = f2bf(W[k * stride + n]);
}

__device__ __forceinline__ void waitge(int* p, int v, int tid) {
  __syncthreads();
  if (tid == 0) {
    long it = 0;
    while (__hip_atomic_load(p, __ATOMIC_RELAXED, __HIP_MEMORY_SCOPE_AGENT) < v) {
      __builtin_amdgcn_s_sleep(1);
      if (++it > (1L << 24)) break;  // valve against true deadlock
    }
  }
  __syncthreads();
}
__device__ __forceinline__ void publish(int* p, int v, int tid) {
  asm volatile("s_waitcnt vmcnt(0)" ::: "memory");
  __syncthreads();
  if (tid == 0) __hip_atomic_store(p, v, __ATOMIC_RELAXED, __HIP_MEMORY_SCOPE_AGENT);
}

#define DLOC(c) ((((c) >> 5) << 9) + (((((c) >> 3) & 3) << 4) + (quad << 2)) * 8 + ((c) & 7))
#define MFMA(a, b, c) __builtin_amdgcn_mfma_f32_16x16x32_bf16((a), (b), (c), 0, 0, 0)

union UB2 { u64 q[2]; bf16x8 v; };
union UB8 { u64 q; ushort4 s; };

__global__ __launch_bounds__(256, 1) void gru_pipe(
    const float* __restrict__ x,
    const float* __restrict__ bz0, const float* __restrict__ bc0,
    const float* __restrict__ bz1, const float* __restrict__ bc1,
    const float* __restrict__ gamma, const float* __restrict__ beta,
    const unsigned short* __restrict__ wsw,
    unsigned short* __restrict__ gws,
    float* __restrict__ out) {
  __shared__ __align__(16) unsigned short lds[59392];  // 116 KB (stage A max)
  const int tid  = threadIdx.x;
  const int wave = tid >> 6;   // 0..3
  const int lane = tid & 63;
  const int l15  = lane & 15;
  const int quad = lane >> 4;
  const int stage = blockIdx.x >> 4;
  const int g     = blockIdx.x & 15;
  const int row0  = g << 4;

  const bf16x8* __restrict__ wsv = (const bf16x8*)wsw;
  unsigned short* ringh = gws + (RB0 >> 1) + (size_t)g * (GSTR >> 1);  // 4 x 32768 ushort
  unsigned short* ringp = ringh + 131072;                              // 4 x 98304 ushort
  int* ctr = (int*)((char*)gws + CTRB) + g * 16;  // [0]A_pub [1]B_pub [2]B_ack [3]C_ack

  if (stage == 0) {
    // ================= Stage A: layer0 =================
    unsigned short* h0f  = lds;            // 8 kt A-frag of h0
    unsigned short* rh0f = lds + 4096;
    unsigned short* xf   = lds + 8192;     // 2 bufs x 2 kt
    unsigned short* xw   = lds + 10240;    // x-part B tiles: 96 x 512 ushort
    for (int u = tid; u < 6144; u += 256) {
      int flat = u << 3, ti = flat >> 9, q = flat & 511, srct;
      if (ti < 64) srct = (ti >> 1) * 10 + 8 + (ti & 1);
      else         srct = 320 + ((ti - 64) >> 1) * 10 + 8 + (ti & 1);
      *(uint4*)(xw + flat) = *(const uint4*)(wsw + srct * 512 + q);
    }
    for (int i = tid; i < 4096; i += 256) h0f[i] = 0;

    bf16x8 pz[4][8], pr[4][8], pc[4][8];   // 96 tiles pinned (unified VGPR/AGPR)
#pragma unroll
    for (int j = 0; j < 4; ++j) {
      const int zt = 4 * wave + j;
#pragma unroll
      for (int k = 0; k < 8; ++k) {
        pz[j][k] = wsv[(zt * 10 + k) * 64 + lane];
        pr[j][k] = wsv[((16 + zt) * 10 + k) * 64 + lane];
        pc[j][k] = wsv[(320 + zt * 10 + k) * 64 + lane];
      }
    }
#pragma unroll
    for (int j = 0; j < 4; ++j)
#pragma unroll
      for (int k = 0; k < 8; ++k)
        asm volatile("" : "+v"(pz[j][k]), "+v"(pr[j][k]), "+v"(pc[j][k]));

    float bzz[4], bzr[4], bcc[4];
    int dloc[4];
#pragma unroll
    for (int j = 0; j < 4; ++j) {
      const int col = 64 * wave + 16 * j + l15;
      bzz[j] = bz0[col]; bzr[j] = bz0[256 + col]; bcc[j] = bc0[col];
      dloc[j] = DLOC(col);
    }
    f32x4 h0s[4] = {{0,0,0,0},{0,0,0,0},{0,0,0,0},{0,0,0,0}};

    const int xrow = tid >> 4, c4 = (tid & 15) << 2;
    const float* xp = x + (size_t)(row0 + xrow) * (SEQL * 64) + c4;
    const int xbase = ((c4 >> 5) << 9) + ((((c4 >> 3) & 3) << 4) + xrow) * 8 + (c4 & 7);
    {
      float4 xv = *(const float4*)xp;
      xf[xbase] = f2bf(sanit(xv.x)); xf[xbase + 1] = f2bf(sanit(xv.y));
      xf[xbase + 2] = f2bf(sanit(xv.z)); xf[xbase + 3] = f2bf(sanit(xv.w));
    }
    __syncthreads();

    for (int ch = 0; ch < NCH; ++ch) {
      if (ch >= DEPTH) waitge(ctr + 2, ch - (DEPTH - 1), tid);   // B freed this slot
      unsigned short* slot = ringh + (ch & (DEPTH - 1)) * (CH * 4096);
      for (int s = 0; s < CH; ++s) {
        const int t = (ch << 3) + s;
        if (s > 0) {  // full 4096-ushort frame of prev step's h0
          u64* dst = (u64*)(slot + (s - 1) * 4096);
          const u64* src = (const u64*)h0f;
#pragma unroll
          for (int q = 0; q < 4; ++q) st8(dst + tid + 256 * q, src[tid + 256 * q]);
        }
        const unsigned short* xb = xf + ((t & 1) << 10);
        const bool havex = (t + 1 < SEQL);
        float4 xn;
        if (havex) xn = *(const float4*)(xp + (t + 1) * 64);

        f32x4 za[4], ra[4];
#pragma unroll
        for (int j = 0; j < 4; ++j) { za[j] = {bzz[j],bzz[j],bzz[j],bzz[j]}; ra[j] = {bzr[j],bzr[j],bzr[j],bzr[j]}; }
#pragma unroll
        for (int k = 0; k < 8; ++k) {
          bf16x8 a = *(const bf16x8*)(h0f + (k << 9) + (lane << 3));
#pragma unroll
          for (int j = 0; j < 4; ++j) { za[j] = MFMA(a, pz[j][k], za[j]); ra[j] = MFMA(a, pr[j][k], ra[j]); }
        }
#pragma unroll
        for (int k = 0; k < 2; ++k) {
          bf16x8 a = *(const bf16x8*)(xb + (k << 9) + (lane << 3));
#pragma unroll
          for (int j = 0; j < 4; ++j) {
            bf16x8 bz_ = *(const bf16x8*)(xw + ((((4 * wave + j) << 1) | k) << 9) + (lane << 3));
            bf16x8 br_ = *(const bf16x8*)(xw + ((((16 + 4 * wave + j) << 1) | k) << 9) + (lane << 3));
            za[j] = MFMA(a, bz_, za[j]); ra[j] = MFMA(a, br_, ra[j]);
          }
        }
        float zg[4][4];
#pragma unroll
        for (int j = 0; j < 4; ++j)
#pragma unroll
          for (int i = 0; i < 4; ++i) {
            zg[j][i] = sigm(za[j][i]);
            rh0f[dloc[j] + i * 8] = f2bf(sigm(ra[j][i]) * h0s[j][i]);
          }
        __syncthreads();

        f32x4 ca[4];
#pragma unroll
        for (int j = 0; j < 4; ++j) ca[j] = {bcc[j],bcc[j],bcc[j],bcc[j]};
#pragma unroll
        for (int k = 0; k < 8; ++k) {
          bf16x8 a = *(const bf16x8*)(rh0f + (k << 9) + (lane << 3));
#pragma unroll
          for (int j = 0; j < 4; ++j) ca[j] = MFMA(a, pc[j][k], ca[j]);
        }
#pragma unroll
        for (int k = 0; k < 2; ++k) {
          bf16x8 a = *(const bf16x8*)(xb + (k << 9) + (lane << 3));
#pragma unroll
          for (int j = 0; j < 4; ++j) {
            bf16x8 bc_ = *(const bf16x8*)(xw + 32768 + ((((4 * wave + j) << 1) | k) << 9) + (lane << 3));
            ca[j] = MFMA(a, bc_, ca[j]);
          }
        }
#pragma unroll
        for (int j = 0; j < 4; ++j)
#pragma unroll
          for (int i = 0; i < 4; ++i) {
            float ht = tanh_(ca[j][i]);
            float hn = h0s[j][i] + zg[j][i] * (ht - h0s[j][i]);
            h0s[j][i] = hn;
            h0f[dloc[j] + i * 8] = f2bf(hn);
          }
        if (havex) {
          unsigned short* xb1 = xf + (((t + 1) & 1) << 10);
          xb1[xbase] = f2bf(sanit(xn.x)); xb1[xbase + 1] = f2bf(sanit(xn.y));
          xb1[xbase + 2] = f2bf(sanit(xn.z)); xb1[xbase + 3] = f2bf(sanit(xn.w));
        }
        __syncthreads();
      }
      {  // final frame of the chunk
        u64* dst = (u64*)(slot + 7 * 4096);
        const u64* src = (const u64*)h0f;
#pragma unroll
        for (int q = 0; q < 4; ++q) st8(dst + tid + 256 * q, src[tid + 256 * q]);
      }
      publish(ctr + 0, ch + 1, tid);
    }
  } else if (stage == 1) {
    // ============ Stage B: layer1 h0-contribution (pure GEMM) ============
    bf16x8 p1[4][8], p2[4][8], p3[4][8];  // Wz1-z, Wz1-r, Wc1 h0-halves (kt 8..15)
#pragma unroll
    for (int j = 0; j < 4; ++j) {
      const int nt = 4 * wave + j;
#pragma unroll
      for (int k = 0; k < 8; ++k) {
        p1[j][k] = wsv[(480 + nt * 16 + 8 + k) * 64 + lane];
        p2[j][k] = wsv[(480 + (16 + nt) * 16 + 8 + k) * 64 + lane];
        p3[j][k] = wsv[(992 + nt * 16 + 8 + k) * 64 + lane];
      }
    }
#pragma unroll
    for (int j = 0; j < 4; ++j)
#pragma unroll
      for (int k = 0; k < 8; ++k)
        asm volatile("" : "+v"(p1[j][k]), "+v"(p2[j][k]), "+v"(p3[j][k]));
    float b1[4], b2[4], b3[4];
#pragma unroll
    for (int j = 0; j < 4; ++j) {
      const int col = 64 * wave + 16 * j + l15;
      b1[j] = bz1[col]; b2[j] = bz1[256 + col]; b3[j] = bc1[col];
    }
    for (int ch = 0; ch < NCH; ++ch) {
      waitge(ctr + 0, ch + 1, tid);                       // A published chunk
      if (ch >= DEPTH) waitge(ctr + 3, ch - (DEPTH - 1), tid);  // C freed p-slot
      const unsigned short* hslot = ringh + (ch & (DEPTH - 1)) * (CH * 4096);
      unsigned short* pslot = ringp + (ch & (DEPTH - 1)) * (CH * 12288);
      u64 cq[2][16];
      {  // preload step 0's frame
        const u64* f0 = (const u64*)hslot;
#pragma unroll
        for (int k = 0; k < 8; ++k) {
          cq[0][2 * k]     = ld8(f0 + (k << 7) + (lane << 1));
          cq[0][2 * k + 1] = ld8(f0 + (k << 7) + (lane << 1) + 1);
        }
      }
#pragma unroll
      for (int s = 0; s < CH; ++s) {
        const int cur = s & 1, nxt = cur ^ 1;
        if (s + 1 < CH) {  // prefetch step s+1 before consuming step s
          const u64* fn = (const u64*)(hslot + (s + 1) * 4096);
#pragma unroll
          for (int k = 0; k < 8; ++k) {
            cq[nxt][2 * k]     = ld8(fn + (k << 7) + (lane << 1));
            cq[nxt][2 * k + 1] = ld8(fn + (k << 7) + (lane << 1) + 1);
          }
        }
        f32x4 za[4] = {{0,0,0,0},{0,0,0,0},{0,0,0,0},{0,0,0,0}};
        f32x4 ra[4] = {{0,0,0,0},{0,0,0,0},{0,0,0,0},{0,0,0,0}};
        f32x4 ca[4] = {{0,0,0,0},{0,0,0,0},{0,0,0,0},{0,0,0,0}};
#pragma unroll
        for (int k = 0; k < 8; ++k) {
          UB2 ub; ub.q[0] = cq[cur][2 * k]; ub.q[1] = cq[cur][2 * k + 1];
          bf16x8 a = ub.v;
#pragma unroll
          for (int j = 0; j < 4; ++j) {
            za[j] = MFMA(a, p1[j][k], za[j]);
            ra[j] = MFMA(a, p2[j][k], ra[j]);
            ca[j] = MFMA(a, p3[j][k], ca[j]);
          }
        }
        u64* pf = (u64*)(pslot + s * 12288);
#pragma unroll
        for (int j = 0; j < 4; ++j) {
          ushort4 vz, vr, vc;
          vz.x = f2bf(za[j][0] + b1[j]); vz.y = f2bf(za[j][1] + b1[j]);
          vz.z = f2bf(za[j][2] + b1[j]); vz.w = f2bf(za[j][3] + b1[j]);
          vr.x = f2bf(ra[j][0] + b2[j]); vr.y = f2bf(ra[j][1] + b2[j]);
          vr.z = f2bf(ra[j][2] + b2[j]); vr.w = f2bf(ra[j][3] + b2[j]);
          vc.x = f2bf(ca[j][0] + b3[j]); vc.y = f2bf(ca[j][1] + b3[j]);
          vc.z = f2bf(ca[j][2] + b3[j]); vc.w = f2bf(ca[j][3] + b3[j]);
          st8(pf + (4 * wave + j) * 64 + lane,      __builtin_bit_cast(u64, vz));
          st8(pf + (16 + 4 * wave + j) * 64 + lane, __builtin_bit_cast(u64, vr));
          st8(pf + (32 + 4 * wave + j) * 64 + lane, __builtin_bit_cast(u64, vc));
        }
      }
      publish(ctr + 1, ch + 1, tid);
      if (tid == 0)
        __hip_atomic_store(ctr + 2, ch + 1, __ATOMIC_RELAXED, __HIP_MEMORY_SCOPE_AGENT);
    }
  } else {
    // ============ Stage C: layer1 recurrence + LN output ============
    unsigned short* h1f  = lds;
    unsigned short* rh1f = lds + 4096;
    bf16x8 q1[4][8], q2[4][8], q3[4][8];  // h1-halves (kt 0..7)
#pragma unroll
    for (int j = 0; j < 4; ++j) {
      const int nt = 4 * wave + j;
#pragma unroll
      for (int k = 0; k < 8; ++k) {
        q1[j][k] = wsv[(480 + nt * 16 + k) * 64 + lane];
        q2[j][k] = wsv[(480 + (16 + nt) * 16 + k) * 64 + lane];
        q3[j][k] = wsv[(992 + nt * 16 + k) * 64 + lane];
      }
    }
#pragma unroll
    for (int j = 0; j < 4; ++j)
#pragma unroll
      for (int k = 0; k < 8; ++k)
        asm volatile("" : "+v"(q1[j][k]), "+v"(q2[j][k]), "+v"(q3[j][k]));
    for (int i = tid; i < 4096; i += 256) h1f[i] = 0;
    int dloc[4];
#pragma unroll
    for (int j = 0; j < 4; ++j) dloc[j] = DLOC(64 * wave + 16 * j + l15);
    f32x4 h1s[4] = {{0,0,0,0},{0,0,0,0},{0,0,0,0},{0,0,0,0}};
    __syncthreads();

    for (int ch = 0; ch < NCH; ++ch) {
      waitge(ctr + 1, ch + 1, tid);
      const unsigned short* pslot = ringp + (ch & (DEPTH - 1)) * (CH * 12288);
      u64 zq[2][4], rq[2][4], cq[2][4];
      {  // preload step 0's partials
        const u64* pf = (const u64*)pslot;
#pragma unroll
        for (int j = 0; j < 4; ++j) {
          zq[0][j] = ld8(pf + (4 * wave + j) * 64 + lane);
          rq[0][j] = ld8(pf + (16 + 4 * wave + j) * 64 + lane);
          cq[0][j] = ld8(pf + (32 + 4 * wave + j) * 64 + lane);
        }
      }
#pragma unroll
      for (int s = 0; s < CH; ++s) {
        const int cur = s & 1, nxt = cur ^ 1;
        if (s + 1 < CH) {  // prefetch step s+1's partials
          const u64* pf = (const u64*)(pslot + (s + 1) * 12288);
#pragma unroll
          for (int j = 0; j < 4; ++j) {
            zq[nxt][j] = ld8(pf + (4 * wave + j) * 64 + lane);
            rq[nxt][j] = ld8(pf + (16 + 4 * wave + j) * 64 + lane);
            cq[nxt][j] = ld8(pf + (32 + 4 * wave + j) * 64 + lane);
          }
        }
        f32x4 za[4] = {{0,0,0,0},{0,0,0,0},{0,0,0,0},{0,0,0,0}};
        f32x4 ra[4] = {{0,0,0,0},{0,0,0,0},{0,0,0,0},{0,0,0,0}};
#pragma unroll
        for (int k = 0; k < 8; ++k) {
          bf16x8 a = *(const bf16x8*)(h1f + (k << 9) + (lane << 3));
#pragma unroll
          for (int j = 0; j < 4; ++j) { za[j] = MFMA(a, q1[j][k], za[j]); ra[j] = MFMA(a, q2[j][k], ra[j]); }
        }
        float zg[4][4];
#pragma unroll
        for (int j = 0; j < 4; ++j) {
          UB8 uz, ur; uz.q = zq[cur][j]; ur.q = rq[cur][j];
#pragma unroll
          for (int i = 0; i < 4; ++i) {
            zg[j][i] = sigm(za[j][i] + bf2f(((const unsigned short*)&uz.s)[i]));
            float r = sigm(ra[j][i] + bf2f(((const unsigned short*)&ur.s)[i]));
            rh1f[dloc[j] + i * 8] = f2bf(r * h1s[j][i]);
          }
        }
        __syncthreads();

        f32x4 ca[4] = {{0,0,0,0},{0,0,0,0},{0,0,0,0},{0,0,0,0}};
#pragma unroll
        for (int k = 0; k < 8; ++k) {
          bf16x8 a = *(const bf16x8*)(rh1f + (k << 9) + (lane << 3));
#pragma unroll
          for (int j = 0; j < 4; ++j) ca[j] = MFMA(a, q3[j][k], ca[j]);
        }
#pragma unroll
        for (int j = 0; j < 4; ++j) {
          UB8 uc; uc.q = cq[cur][j];
#pragma unroll
          for (int i = 0; i < 4; ++i) {
            float ht = tanh_(ca[j][i] + bf2f(((const unsigned short*)&uc.s)[i]));
            float hn = h1s[j][i] + zg[j][i] * (ht - h1s[j][i]);
            h1s[j][i] = hn;
            h1f[dloc[j] + i * 8] = f2bf(hn);
          }
        }
        __syncthreads();
      }
      publish(ctr + 3, ch + 1, tid);
    }

    // LayerNorm from fp32 h1 state via LDS staging
    float* h1buf = (float*)lds;   // 16 x 256 fp32 = 16 KB
#pragma unroll
    for (int j = 0; j < 4; ++j)
#pragma unroll
      for (int i = 0; i < 4; ++i)
        h1buf[(quad * 4 + i) * 256 + 64 * wave + 16 * j + l15] = h1s[j][i];
    __syncthreads();

    const int r = tid >> 4, cl = tid & 15;
    float v[16], s = 0.f, sq = 0.f;
#pragma unroll
    for (int jj = 0; jj < 16; ++jj) {
      v[jj] = h1buf[r * 256 + cl + (jj << 4)];
      s += v[jj]; sq += v[jj] * v[jj];
    }
#pragma unroll
    for (int off = 8; off > 0; off >>= 1) {   // 16-lane group reduce
      s  += __shfl_xor(s, off);
      sq += __shfl_xor(sq, off);
    }
    const float mean = s * (1.f / 256.f);
    const float var  = sq * (1.f / 256.f) - mean * mean;
    const float rstd = rsqrtf(var + 1e-5f);
    float* op = out + (size_t)(row0 + r) * 256;
#pragma unroll
    for (int jj = 0; jj < 16; ++jj) {
      const int c = cl + (jj << 4);
      op[c] = (v[jj] - mean) * rstd * gamma[c] + beta[c];
    }
  }
}

extern "C" void kernel_launch(void* const* d_in, const int* in_sizes, int n_in,
                              void* d_out, int out_size, void* d_ws, size_t ws_size,
                              hipStream_t stream) {
  const float* x     = (const float*)d_in[0];
  const float* Wz0   = (const float*)d_in[1];
  const float* bz0   = (const float*)d_in[2];
  const float* Wc0   = (const float*)d_in[3];
  const float* bc0   = (const float*)d_in[4];
  const float* Wz1   = (const float*)d_in[5];
  const float* bz1   = (const float*)d_in[6];
  const float* Wc1   = (const float*)d_in[7];
  const float* bc1   = (const float*)d_in[8];
  const float* gamma = (const float*)d_in[9];
  const float* beta  = (const float*)d_in[10];
  unsigned short* ws = (unsigned short*)d_ws;
  float* out = (float*)d_out;

  hipMemsetAsync((char*)d_ws + CTRB, 0, 1024, stream);
  hipLaunchKernelGGL(prep_weights, dim3(2496), dim3(256), 0, stream, Wz0, Wc0, Wz1, Wc1, ws);
  hipLaunchKernelGGL(gru_pipe, dim3(48), dim3(256), 0, stream,
                     x, bz0, bc0, bz1, bc1, gamma, beta, ws, ws, out);
}

// Round 12
// 3103.021 us; speedup vs baseline: 1.0472x; 1.0472x over previous
//
#include <hip/hip_runtime.h>

// TimeframeEncoder R12: R11 with the measured bottleneck fixed: the per-step
// ring loads were serialized relaxed-atomic loads (~900cyc EACH, ~1
// outstanding/wave -> B: 16x900 = 6.0us/step = the whole 3.2ms). Replaced
// with batched inline-asm load blocks (8x dwordx4 / 12x dwordx2, ONE
// s_waitcnt vmcnt(0), sc0 sc1 = same device-coherent encoding the atomics
// emit). Stores stay __hip_atomic_store (fire-and-forget). Everything else
// (grid 48, stage = blockIdx>>4, depth-4 rings, counters) identical to R11.

#define SEQL 512
#define CH 8
#define NCH 64
#define DEPTH 4

#define RB0  1310720u                   // rings base (weights end 1,277,952)
#define GSTR 1048576u                   // per group: 4x64KB h0 + 4x192KB partials
#define CTRB (RB0 + 16u * GSTR)         // counters: 16 groups x 64 B

typedef __bf16 bf16x8 __attribute__((ext_vector_type(8)));
typedef float f32x4 __attribute__((ext_vector_type(4)));
typedef unsigned int u32x4 __attribute__((ext_vector_type(4)));
typedef unsigned long long u64;

__device__ __forceinline__ unsigned short f2bf(float f) {
  unsigned int u = __builtin_bit_cast(unsigned int, f);
  u += 0x7fffu + ((u >> 16) & 1u);
  return (unsigned short)(u >> 16);
}
__device__ __forceinline__ float bf2f(unsigned short u) {
  unsigned int v = ((unsigned int)u) << 16;
  return __builtin_bit_cast(float, v);
}
__device__ __forceinline__ float sigm(float x) { return 1.0f / (1.0f + __expf(-x)); }
__device__ __forceinline__ float tanh_(float x) { return 1.0f - 2.0f / (__expf(2.0f * x) + 1.0f); }
__device__ __forceinline__ float sanit(float v) {
  if (!(v == v)) return 0.f;
  if (isinf(v)) return v > 0.f ? 10.f : -10.f;
  return v;
}

// agent-coherent stores (fire-and-forget; proven correct R8/R11)
__device__ __forceinline__ void st8(u64* p, u64 v) {
  __hip_atomic_store(p, v, __ATOMIC_RELAXED, __HIP_MEMORY_SCOPE_AGENT);
}

// ---- batched device-coherent load blocks: N loads in flight, ONE waitcnt ----
// sc0 sc1 = bypass stale L1/L2, read from coherence point (same encoding as
// __hip_atomic_load relaxed-agent, but batched instead of serialized).
__device__ __forceinline__ void ld_frame8(const unsigned short* base, int lane, u32x4* c) {
  const char* p0 = (const char*)base + lane * 16;
  const char* p4 = p0 + 4096;
  asm volatile(
      "global_load_dwordx4 %0, %8, off sc0 sc1\n\t"
      "global_load_dwordx4 %1, %8, off offset:1024 sc0 sc1\n\t"
      "global_load_dwordx4 %2, %8, off offset:2048 sc0 sc1\n\t"
      "global_load_dwordx4 %3, %8, off offset:3072 sc0 sc1\n\t"
      "global_load_dwordx4 %4, %9, off sc0 sc1\n\t"
      "global_load_dwordx4 %5, %9, off offset:1024 sc0 sc1\n\t"
      "global_load_dwordx4 %6, %9, off offset:2048 sc0 sc1\n\t"
      "global_load_dwordx4 %7, %9, off offset:3072 sc0 sc1\n\t"
      "s_waitcnt vmcnt(0)"
      : "=&v"(c[0]), "=&v"(c[1]), "=&v"(c[2]), "=&v"(c[3]),
        "=&v"(c[4]), "=&v"(c[5]), "=&v"(c[6]), "=&v"(c[7])
      : "v"(p0), "v"(p4)
      : "memory");
}
__device__ __forceinline__ void ld_part12(const unsigned short* pf, int wave, int lane,
                                          u64* z, u64* r, u64* c) {
  const char* p0 = (const char*)pf + ((4 * wave) * 64 + lane) * 8;
  const char* p1 = p0 + 8192;
  const char* p2 = p0 + 16384;
  asm volatile(
      "global_load_dwordx2 %0, %12, off sc0 sc1\n\t"
      "global_load_dwordx2 %1, %12, off offset:512 sc0 sc1\n\t"
      "global_load_dwordx2 %2, %12, off offset:1024 sc0 sc1\n\t"
      "global_load_dwordx2 %3, %12, off offset:1536 sc0 sc1\n\t"
      "global_load_dwordx2 %4, %13, off sc0 sc1\n\t"
      "global_load_dwordx2 %5, %13, off offset:512 sc0 sc1\n\t"
      "global_load_dwordx2 %6, %13, off offset:1024 sc0 sc1\n\t"
      "global_load_dwordx2 %7, %13, off offset:1536 sc0 sc1\n\t"
      "global_load_dwordx2 %8, %14, off sc0 sc1\n\t"
      "global_load_dwordx2 %9, %14, off offset:512 sc0 sc1\n\t"
      "global_load_dwordx2 %10, %14, off offset:1024 sc0 sc1\n\t"
      "global_load_dwordx2 %11, %14, off offset:1536 sc0 sc1\n\t"
      "s_waitcnt vmcnt(0)"
      : "=&v"(z[0]), "=&v"(z[1]), "=&v"(z[2]), "=&v"(z[3]),
        "=&v"(r[0]), "=&v"(r[1]), "=&v"(r[2]), "=&v"(r[3]),
        "=&v"(c[0]), "=&v"(c[1]), "=&v"(c[2]), "=&v"(c[3])
      : "v"(p0), "v"(p1), "v"(p2)
      : "memory");
}

// Weight prep (layout verified R1-R11): bf16 B-fragments, tile = 512 ushort,
// lane L holds B[k=(L>>4)*8+j][n=L&15]. Wz0p tiles [0,320) (nt<32,kt<10);
// Wc0p base 320 (nt<16,kt<10); Wz1p base 480 (nt<32,kt<16); Wc1p base 992.
__global__ __launch_bounds__(256) void prep_weights(
    const float* __restrict__ Wz0, const float* __restrict__ Wc0,
    const float* __restrict__ Wz1, const float* __restrict__ Wc1,
    unsigned short* __restrict__ ws) {
  int idx = blockIdx.x * 256 + threadIdx.x;  // 638976 threads
  const float* W;
  int stride, KT, base;
  if (idx < 163840)      { W = Wz0; stride = 768; KT = 10; base = 0; }
  else if (idx < 245760) { W = Wc0; stride = 256; KT = 10; base = 163840; idx -= 163840; }
  else if (idx < 507904) { W = Wz1; stride = 768; KT = 16; base = 245760; idx -= 245760; }
  else                   { W = Wc1; stride = 256; KT = 16; base = 507904; idx -= 507904; }
  int tile = idx >> 9;
  int t = idx & 511;
  int nt = tile / KT;
  int kt = tile - nt * KT;
  int n15 = t & 15;
  int klocal = t >> 4;
  int k = (kt << 5) + klocal;
  int n = (nt << 4) + n15;
  int lane = ((klocal >> 3) << 4) | n15;
  int j = klocal & 7;
  ws[base + (tile << 9) + (lane << 3) + j] = f2bf(W[k * stride + n]);
}

__device__ __forceinline__ void waitge(int* p, int v, int tid) {
  __syncthreads();
  if (tid == 0) {
    long it = 0;
    while (__hip_atomic_load(p, __ATOMIC_RELAXED, __HIP_MEMORY_SCOPE_AGENT) < v) {
      __builtin_amdgcn_s_sleep(1);
      if (++it > (1L << 24)) break;  // valve against true deadlock
    }
  }
  __syncthreads();
}
__device__ __forceinline__ void publish(int* p, int v, int tid) {
  asm volatile("s_waitcnt vmcnt(0)" ::: "memory");
  __syncthreads();
  if (tid == 0) __hip_atomic_store(p, v, __ATOMIC_RELAXED, __HIP_MEMORY_SCOPE_AGENT);
}

#define DLOC(c) ((((c) >> 5) << 9) + (((((c) >> 3) & 3) << 4) + (quad << 2)) * 8 + ((c) & 7))
#define MFMA(a, b, c) __builtin_amdgcn_mfma_f32_16x16x32_bf16((a), (b), (c), 0, 0, 0)

union UB  { u32x4 q; bf16x8 v; };
union UB8 { u64 q; ushort4 s; };

__global__ __launch_bounds__(256, 1) void gru_pipe(
    const float* __restrict__ x,
    const float* __restrict__ bz0, const float* __restrict__ bc0,
    const float* __restrict__ bz1, const float* __restrict__ bc1,
    const float* __restrict__ gamma, const float* __restrict__ beta,
    const unsigned short* __restrict__ wsw,
    unsigned short* __restrict__ gws,
    float* __restrict__ out) {
  __shared__ __align__(16) unsigned short lds[59392];  // 116 KB (stage A max)
  const int tid  = threadIdx.x;
  const int wave = tid >> 6;   // 0..3
  const int lane = tid & 63;
  const int l15  = lane & 15;
  const int quad = lane >> 4;
  const int stage = blockIdx.x >> 4;
  const int g     = blockIdx.x & 15;
  const int row0  = g << 4;

  const bf16x8* __restrict__ wsv = (const bf16x8*)wsw;
  unsigned short* ringh = gws + (RB0 >> 1) + (size_t)g * (GSTR >> 1);  // 4 x 32768 ushort
  unsigned short* ringp = ringh + 131072;                              // 4 x 98304 ushort
  int* ctr = (int*)((char*)gws + CTRB) + g * 16;  // [0]A_pub [1]B_pub [2]B_ack [3]C_ack

  if (stage == 0) {
    // ================= Stage A: layer0 =================
    unsigned short* h0f  = lds;            // 8 kt A-frag of h0
    unsigned short* rh0f = lds + 4096;
    unsigned short* xf   = lds + 8192;     // 2 bufs x 2 kt
    unsigned short* xw   = lds + 10240;    // x-part B tiles: 96 x 512 ushort
    for (int u = tid; u < 6144; u += 256) {
      int flat = u << 3, ti = flat >> 9, q = flat & 511, srct;
      if (ti < 64) srct = (ti >> 1) * 10 + 8 + (ti & 1);
      else         srct = 320 + ((ti - 64) >> 1) * 10 + 8 + (ti & 1);
      *(uint4*)(xw + flat) = *(const uint4*)(wsw + srct * 512 + q);
    }
    for (int i = tid; i < 4096; i += 256) h0f[i] = 0;

    bf16x8 pz[4][8], pr[4][8], pc[4][8];   // 96 tiles pinned (unified VGPR/AGPR)
#pragma unroll
    for (int j = 0; j < 4; ++j) {
      const int zt = 4 * wave + j;
#pragma unroll
      for (int k = 0; k < 8; ++k) {
        pz[j][k] = wsv[(zt * 10 + k) * 64 + lane];
        pr[j][k] = wsv[((16 + zt) * 10 + k) * 64 + lane];
        pc[j][k] = wsv[(320 + zt * 10 + k) * 64 + lane];
      }
    }
#pragma unroll
    for (int j = 0; j < 4; ++j)
#pragma unroll
      for (int k = 0; k < 8; ++k)
        asm volatile("" : "+v"(pz[j][k]), "+v"(pr[j][k]), "+v"(pc[j][k]));

    float bzz[4], bzr[4], bcc[4];
    int dloc[4];
#pragma unroll
    for (int j = 0; j < 4; ++j) {
      const int col = 64 * wave + 16 * j + l15;
      bzz[j] = bz0[col]; bzr[j] = bz0[256 + col]; bcc[j] = bc0[col];
      dloc[j] = DLOC(col);
    }
    f32x4 h0s[4] = {{0,0,0,0},{0,0,0,0},{0,0,0,0},{0,0,0,0}};

    const int xrow = tid >> 4, c4 = (tid & 15) << 2;
    const float* xp = x + (size_t)(row0 + xrow) * (SEQL * 64) + c4;
    const int xbase = ((c4 >> 5) << 9) + ((((c4 >> 3) & 3) << 4) + xrow) * 8 + (c4 & 7);
    {
      float4 xv = *(const float4*)xp;
      xf[xbase] = f2bf(sanit(xv.x)); xf[xbase + 1] = f2bf(sanit(xv.y));
      xf[xbase + 2] = f2bf(sanit(xv.z)); xf[xbase + 3] = f2bf(sanit(xv.w));
    }
    __syncthreads();

    for (int ch = 0; ch < NCH; ++ch) {
      if (ch >= DEPTH) waitge(ctr + 2, ch - (DEPTH - 1), tid);   // B freed this slot
      unsigned short* slot = ringh + (ch & (DEPTH - 1)) * (CH * 4096);
      for (int s = 0; s < CH; ++s) {
        const int t = (ch << 3) + s;
        if (s > 0) {  // full 4096-ushort frame of prev step's h0
          u64* dst = (u64*)(slot + (s - 1) * 4096);
          const u64* src = (const u64*)h0f;
#pragma unroll
          for (int q = 0; q < 4; ++q) st8(dst + tid + 256 * q, src[tid + 256 * q]);
        }
        const unsigned short* xb = xf + ((t & 1) << 10);
        const bool havex = (t + 1 < SEQL);
        float4 xn;
        if (havex) xn = *(const float4*)(xp + (t + 1) * 64);

        f32x4 za[4], ra[4];
#pragma unroll
        for (int j = 0; j < 4; ++j) { za[j] = {bzz[j],bzz[j],bzz[j],bzz[j]}; ra[j] = {bzr[j],bzr[j],bzr[j],bzr[j]}; }
#pragma unroll
        for (int k = 0; k < 8; ++k) {
          bf16x8 a = *(const bf16x8*)(h0f + (k << 9) + (lane << 3));
#pragma unroll
          for (int j = 0; j < 4; ++j) { za[j] = MFMA(a, pz[j][k], za[j]); ra[j] = MFMA(a, pr[j][k], ra[j]); }
        }
#pragma unroll
        for (int k = 0; k < 2; ++k) {
          bf16x8 a = *(const bf16x8*)(xb + (k << 9) + (lane << 3));
#pragma unroll
          for (int j = 0; j < 4; ++j) {
            bf16x8 bz_ = *(const bf16x8*)(xw + ((((4 * wave + j) << 1) | k) << 9) + (lane << 3));
            bf16x8 br_ = *(const bf16x8*)(xw + ((((16 + 4 * wave + j) << 1) | k) << 9) + (lane << 3));
            za[j] = MFMA(a, bz_, za[j]); ra[j] = MFMA(a, br_, ra[j]);
          }
        }
        float zg[4][4];
#pragma unroll
        for (int j = 0; j < 4; ++j)
#pragma unroll
          for (int i = 0; i < 4; ++i) {
            zg[j][i] = sigm(za[j][i]);
            rh0f[dloc[j] + i * 8] = f2bf(sigm(ra[j][i]) * h0s[j][i]);
          }
        __syncthreads();

        f32x4 ca[4];
#pragma unroll
        for (int j = 0; j < 4; ++j) ca[j] = {bcc[j],bcc[j],bcc[j],bcc[j]};
#pragma unroll
        for (int k = 0; k < 8; ++k) {
          bf16x8 a = *(const bf16x8*)(rh0f + (k << 9) + (lane << 3));
#pragma unroll
          for (int j = 0; j < 4; ++j) ca[j] = MFMA(a, pc[j][k], ca[j]);
        }
#pragma unroll
        for (int k = 0; k < 2; ++k) {
          bf16x8 a = *(const bf16x8*)(xb + (k << 9) + (lane << 3));
#pragma unroll
          for (int j = 0; j < 4; ++j) {
            bf16x8 bc_ = *(const bf16x8*)(xw + 32768 + ((((4 * wave + j) << 1) | k) << 9) + (lane << 3));
            ca[j] = MFMA(a, bc_, ca[j]);
          }
        }
#pragma unroll
        for (int j = 0; j < 4; ++j)
#pragma unroll
          for (int i = 0; i < 4; ++i) {
            float ht = tanh_(ca[j][i]);
            float hn = h0s[j][i] + zg[j][i] * (ht - h0s[j][i]);
            h0s[j][i] = hn;
            h0f[dloc[j] + i * 8] = f2bf(hn);
          }
        if (havex) {
          unsigned short* xb1 = xf + (((t + 1) & 1) << 10);
          xb1[xbase] = f2bf(sanit(xn.x)); xb1[xbase + 1] = f2bf(sanit(xn.y));
          xb1[xbase + 2] = f2bf(sanit(xn.z)); xb1[xbase + 3] = f2bf(sanit(xn.w));
        }
        __syncthreads();
      }
      {  // final frame of the chunk
        u64* dst = (u64*)(slot + 7 * 4096);
        const u64* src = (const u64*)h0f;
#pragma unroll
        for (int q = 0; q < 4; ++q) st8(dst + tid + 256 * q, src[tid + 256 * q]);
      }
      publish(ctr + 0, ch + 1, tid);
    }
  } else if (stage == 1) {
    // ============ Stage B: layer1 h0-contribution (pure GEMM) ============
    bf16x8 p1[4][8], p2[4][8], p3[4][8];  // Wz1-z, Wz1-r, Wc1 h0-halves (kt 8..15)
#pragma unroll
    for (int j = 0; j < 4; ++j) {
      const int nt = 4 * wave + j;
#pragma unroll
      for (int k = 0; k < 8; ++k) {
        p1[j][k] = wsv[(480 + nt * 16 + 8 + k) * 64 + lane];
        p2[j][k] = wsv[(480 + (16 + nt) * 16 + 8 + k) * 64 + lane];
        p3[j][k] = wsv[(992 + nt * 16 + 8 + k) * 64 + lane];
      }
    }
#pragma unroll
    for (int j = 0; j < 4; ++j)
#pragma unroll
      for (int k = 0; k < 8; ++k)
        asm volatile("" : "+v"(p1[j][k]), "+v"(p2[j][k]), "+v"(p3[j][k]));
    float b1[4], b2[4], b3[4];
#pragma unroll
    for (int j = 0; j < 4; ++j) {
      const int col = 64 * wave + 16 * j + l15;
      b1[j] = bz1[col]; b2[j] = bz1[256 + col]; b3[j] = bc1[col];
    }
    for (int ch = 0; ch < NCH; ++ch) {
      waitge(ctr + 0, ch + 1, tid);                       // A published chunk
      if (ch >= DEPTH) waitge(ctr + 3, ch - (DEPTH - 1), tid);  // C freed p-slot
      const unsigned short* hslot = ringh + (ch & (DEPTH - 1)) * (CH * 4096);
      unsigned short* pslot = ringp + (ch & (DEPTH - 1)) * (CH * 12288);
      for (int s = 0; s < CH; ++s) {
        u32x4 cf[8];
        ld_frame8(hslot + s * 4096, lane, cf);   // 8 loads in flight, 1 waitcnt
        f32x4 za[4] = {{0,0,0,0},{0,0,0,0},{0,0,0,0},{0,0,0,0}};
        f32x4 ra[4] = {{0,0,0,0},{0,0,0,0},{0,0,0,0},{0,0,0,0}};
        f32x4 ca[4] = {{0,0,0,0},{0,0,0,0},{0,0,0,0},{0,0,0,0}};
#pragma unroll
        for (int k = 0; k < 8; ++k) {
          UB ub; ub.q = cf[k];
          bf16x8 a = ub.v;
#pragma unroll
          for (int j = 0; j < 4; ++j) {
            za[j] = MFMA(a, p1[j][k], za[j]);
            ra[j] = MFMA(a, p2[j][k], ra[j]);
            ca[j] = MFMA(a, p3[j][k], ca[j]);
          }
        }
        u64* pf = (u64*)(pslot + s * 12288);
#pragma unroll
        for (int j = 0; j < 4; ++j) {
          ushort4 vz, vr, vc;
          vz.x = f2bf(za[j][0] + b1[j]); vz.y = f2bf(za[j][1] + b1[j]);
          vz.z = f2bf(za[j][2] + b1[j]); vz.w = f2bf(za[j][3] + b1[j]);
          vr.x = f2bf(ra[j][0] + b2[j]); vr.y = f2bf(ra[j][1] + b2[j]);
          vr.z = f2bf(ra[j][2] + b2[j]); vr.w = f2bf(ra[j][3] + b2[j]);
          vc.x = f2bf(ca[j][0] + b3[j]); vc.y = f2bf(ca[j][1] + b3[j]);
          vc.z = f2bf(ca[j][2] + b3[j]); vc.w = f2bf(ca[j][3] + b3[j]);
          st8(pf + (4 * wave + j) * 64 + lane,      __builtin_bit_cast(u64, vz));
          st8(pf + (16 + 4 * wave + j) * 64 + lane, __builtin_bit_cast(u64, vr));
          st8(pf + (32 + 4 * wave + j) * 64 + lane, __builtin_bit_cast(u64, vc));
        }
      }
      publish(ctr + 1, ch + 1, tid);
      if (tid == 0)
        __hip_atomic_store(ctr + 2, ch + 1, __ATOMIC_RELAXED, __HIP_MEMORY_SCOPE_AGENT);
    }
  } else {
    // ============ Stage C: layer1 recurrence + LN output ============
    unsigned short* h1f  = lds;
    unsigned short* rh1f = lds + 4096;
    bf16x8 q1[4][8], q2[4][8], q3[4][8];  // h1-halves (kt 0..7)
#pragma unroll
    for (int j = 0; j < 4; ++j) {
      const int nt = 4 * wave + j;
#pragma unroll
      for (int k = 0; k < 8; ++k) {
        q1[j][k] = wsv[(480 + nt * 16 + k) * 64 + lane];
        q2[j][k] = wsv[(480 + (16 + nt) * 16 + k) * 64 + lane];
        q3[j][k] = wsv[(992 + nt * 16 + k) * 64 + lane];
      }
    }
#pragma unroll
    for (int j = 0; j < 4; ++j)
#pragma unroll
      for (int k = 0; k < 8; ++k)
        asm volatile("" : "+v"(q1[j][k]), "+v"(q2[j][k]), "+v"(q3[j][k]));
    for (int i = tid; i < 4096; i += 256) h1f[i] = 0;
    int dloc[4];
#pragma unroll
    for (int j = 0; j < 4; ++j) dloc[j] = DLOC(64 * wave + 16 * j + l15);
    f32x4 h1s[4] = {{0,0,0,0},{0,0,0,0},{0,0,0,0},{0,0,0,0}};
    __syncthreads();

    for (int ch = 0; ch < NCH; ++ch) {
      waitge(ctr + 1, ch + 1, tid);
      const unsigned short* pslot = ringp + (ch & (DEPTH - 1)) * (CH * 12288);
      for (int s = 0; s < CH; ++s) {
        u64 zq[4], rq[4], cq[4];
        ld_part12(pslot + s * 12288, wave, lane, zq, rq, cq);  // 12 in flight, 1 waitcnt
        f32x4 za[4] = {{0,0,0,0},{0,0,0,0},{0,0,0,0},{0,0,0,0}};
        f32x4 ra[4] = {{0,0,0,0},{0,0,0,0},{0,0,0,0},{0,0,0,0}};
#pragma unroll
        for (int k = 0; k < 8; ++k) {
          bf16x8 a = *(const bf16x8*)(h1f + (k << 9) + (lane << 3));
#pragma unroll
          for (int j = 0; j < 4; ++j) { za[j] = MFMA(a, q1[j][k], za[j]); ra[j] = MFMA(a, q2[j][k], ra[j]); }
        }
        float zg[4][4];
#pragma unroll
        for (int j = 0; j < 4; ++j) {
          UB8 uz, ur; uz.q = zq[j]; ur.q = rq[j];
#pragma unroll
          for (int i = 0; i < 4; ++i) {
            zg[j][i] = sigm(za[j][i] + bf2f(((const unsigned short*)&uz.s)[i]));
            float r = sigm(ra[j][i] + bf2f(((const unsigned short*)&ur.s)[i]));
            rh1f[dloc[j] + i * 8] = f2bf(r * h1s[j][i]);
          }
        }
        __syncthreads();

        f32x4 ca[4] = {{0,0,0,0},{0,0,0,0},{0,0,0,0},{0,0,0,0}};
#pragma unroll
        for (int k = 0; k < 8; ++k) {
          bf16x8 a = *(const bf16x8*)(rh1f + (k << 9) + (lane << 3));
#pragma unroll
          for (int j = 0; j < 4; ++j) ca[j] = MFMA(a, q3[j][k], ca[j]);
        }
#pragma unroll
        for (int j = 0; j < 4; ++j) {
          UB8 uc; uc.q = cq[j];
#pragma unroll
          for (int i = 0; i < 4; ++i) {
            float ht = tanh_(ca[j][i] + bf2f(((const unsigned short*)&uc.s)[i]));
            float hn = h1s[j][i] + zg[j][i] * (ht - h1s[j][i]);
            h1s[j][i] = hn;
            h1f[dloc[j] + i * 8] = f2bf(hn);
          }
        }
        __syncthreads();
      }
      publish(ctr + 3, ch + 1, tid);
    }

    // LayerNorm from fp32 h1 state via LDS staging
    float* h1buf = (float*)lds;   // 16 x 256 fp32 = 16 KB
#pragma unroll
    for (int j = 0; j < 4; ++j)
#pragma unroll
      for (int i = 0; i < 4; ++i)
        h1buf[(quad * 4 + i) * 256 + 64 * wave + 16 * j + l15] = h1s[j][i];
    __syncthreads();

    const int r = tid >> 4, cl = tid & 15;
    float v[16], s = 0.f, sq = 0.f;
#pragma unroll
    for (int jj = 0; jj < 16; ++jj) {
      v[jj] = h1buf[r * 256 + cl + (jj << 4)];
      s += v[jj]; sq += v[jj] * v[jj];
    }
#pragma unroll
    for (int off = 8; off > 0; off >>= 1) {   // 16-lane group reduce
      s  += __shfl_xor(s, off);
      sq += __shfl_xor(sq, off);
    }
    const float mean = s * (1.f / 256.f);
    const float var  = sq * (1.f / 256.f) - mean * mean;
    const float rstd = rsqrtf(var + 1e-5f);
    float* op = out + (size_t)(row0 + r) * 256;
#pragma unroll
    for (int jj = 0; jj < 16; ++jj) {
      const int c = cl + (jj << 4);
      op[c] = (v[jj] - mean) * rstd * gamma[c] + beta[c];
    }
  }
}

extern "C" void kernel_launch(void* const* d_in, const int* in_sizes, int n_in,
                              void* d_out, int out_size, void* d_ws, size_t ws_size,
                              hipStream_t stream) {
  const float* x     = (const float*)d_in[0];
  const float* Wz0   = (const float*)d_in[1];
  const float* bz0   = (const float*)d_in[2];
  const float* Wc0   = (const float*)d_in[3];
  const float* bc0   = (const float*)d_in[4];
  const float* Wz1   = (const float*)d_in[5];
  const float* bz1   = (const float*)d_in[6];
  const float* Wc1   = (const float*)d_in[7];
  const float* bc1   = (const float*)d_in[8];
  const float* gamma = (const float*)d_in[9];
  const float* beta  = (const float*)d_in[10];
  unsigned short* ws = (unsigned short*)d_ws;
  float* out = (float*)d_out;

  hipMemsetAsync((char*)d_ws + CTRB, 0, 1024, stream);
  hipLaunchKernelGGL(prep_weights, dim3(2496), dim3(256), 0, stream, Wz0, Wc0, Wz1, Wc1, ws);
  hipLaunchKernelGGL(gru_pipe, dim3(48), dim3(256), 0, stream,
                     x, bz0, bc0, bz1, bc1, gamma, beta, ws, ws, out);
}